// Round 1
// baseline (2933.134 us; speedup 1.0000x reference)
//
#include <hip/hip_runtime.h>
#include <hip/hip_bf16.h>
#include <math.h>

#define H 1024
#define L_ENC 128
#define V 50257
#define STEPS 32
#define STOP_ID 658

// workspace layout (float offsets)
#define WS_H     0        // 1024  hidden state h
#define WS_HNEW  1024     // 1024  candidate h_new
#define WS_GH    2048     // 3072  gh = h @ whh.T + bhh
#define WS_ALOG  5120     // 128   attention logits
#define WS_X     5248     // 1024  x = relu(comb)
#define WS_PMAX  6272     // 508   per-block argmax value
#define WS_PIDX  6784     // 508   per-block argmax index (int)
#define WS_TOK   7296     // int   current token
#define WS_DONE  7297     // int   done flag

#define NB_OUT 508        // 508 blocks * 99 rows >= 50257

__global__ __launch_bounds__(1024) void k_init(const int* __restrict__ dec_in,
                                               const float* __restrict__ h0,
                                               float* __restrict__ ws) {
    int t = threadIdx.x;
    ws[WS_H + t] = h0[t];
    if (t == 0) {
        ((int*)(ws + WS_TOK))[0]  = dec_in[0];
        ((int*)(ws + WS_DONE))[0] = 0;
    }
}

// blocks 0..31: attention logit rows (4/block, one per wave)
// blocks 32..799: gh rows (4/block, one per wave)
__global__ __launch_bounds__(256) void k_pre(const float* __restrict__ embedding,
                                             const float* __restrict__ attn_w,
                                             const float* __restrict__ attn_b,
                                             const float* __restrict__ whh,
                                             const float* __restrict__ bhh,
                                             float* __restrict__ ws) {
    const int wave = threadIdx.x >> 6, lane = threadIdx.x & 63;
    const int tok = ((const int*)(ws + WS_TOK))[0];
    const float4* h4 = (const float4*)(ws + WS_H);
    if (blockIdx.x < 32) {
        const int r = blockIdx.x * 4 + wave;            // 0..127
        const float4* w4 = (const float4*)(attn_w + (size_t)r * 2048);
        const float4* e4 = (const float4*)(embedding + (size_t)tok * H);
        float s = 0.f;
        for (int m = 0; m < 8; ++m) {
            int j = lane + (m << 6);                    // 0..511 float4 index
            float4 a = w4[j];
            float4 c = (j < 256) ? e4[j] : h4[j - 256];
            s += a.x * c.x + a.y * c.y + a.z * c.z + a.w * c.w;
        }
        for (int o = 32; o; o >>= 1) s += __shfl_down(s, o);
        if (lane == 0) ws[WS_ALOG + r] = s + attn_b[r];
    } else {
        const int r = (blockIdx.x - 32) * 4 + wave;     // 0..3071
        const float4* w4 = (const float4*)(whh + (size_t)r * H);
        float s = 0.f;
        for (int m = 0; m < 4; ++m) {
            int j = lane + (m << 6);
            float4 a = w4[j], b = h4[j];
            s += a.x * b.x + a.y * b.y + a.z * b.z + a.w * b.w;
        }
        for (int o = 32; o; o >>= 1) s += __shfl_down(s, o);
        if (lane == 0) ws[WS_GH + r] = s + bhh[r];
    }
}

// 64 blocks: redundant softmax + ctx, then 16 comb rows per block
__global__ __launch_bounds__(256) void k_ctx_comb(const float* __restrict__ embedding,
                                                  const float* __restrict__ enc,
                                                  const float* __restrict__ comb_w,
                                                  const float* __restrict__ comb_b,
                                                  float* __restrict__ ws) {
    __shared__ float s_aw[L_ENC];
    __shared__ __align__(16) float s_cat[2048];
    const int t = threadIdx.x;
    const int tok = ((const int*)(ws + WS_TOK))[0];

    if (t < L_ENC) s_aw[t] = ws[WS_ALOG + t];
    __syncthreads();
    float mx = -INFINITY;
    for (int l = 0; l < L_ENC; ++l) mx = fmaxf(mx, s_aw[l]);
    __syncthreads();
    if (t < L_ENC) s_aw[t] = expf(s_aw[t] - mx);
    __syncthreads();
    float ssum = 0.f;
    for (int l = 0; l < L_ENC; ++l) ssum += s_aw[l];
    const float inv = 1.f / ssum;

    // cat = [emb ; ctx], each thread owns one float4 of each half
    float4* cat4 = (float4*)s_cat;
    const float4* e4   = (const float4*)(embedding + (size_t)tok * H);
    const float4* enc4 = (const float4*)enc;   // [128][256]
    cat4[t] = e4[t];
    float4 c = make_float4(0.f, 0.f, 0.f, 0.f);
    for (int l = 0; l < L_ENC; ++l) {
        float a = s_aw[l];
        float4 e = enc4[l * 256 + t];
        c.x += a * e.x; c.y += a * e.y; c.z += a * e.z; c.w += a * e.w;
    }
    cat4[256 + t] = make_float4(c.x * inv, c.y * inv, c.z * inv, c.w * inv);
    __syncthreads();

    const int wave = t >> 6, lane = t & 63;
    for (int k = 0; k < 4; ++k) {
        const int r = blockIdx.x * 16 + wave * 4 + k;   // 0..1023
        const float4* w4 = (const float4*)(comb_w + (size_t)r * 2048);
        float s = 0.f;
        for (int m = 0; m < 8; ++m) {
            int j = lane + (m << 6);
            float4 a = w4[j], b = cat4[j];
            s += a.x * b.x + a.y * b.y + a.z * b.z + a.w * b.w;
        }
        for (int o = 32; o; o >>= 1) s += __shfl_down(s, o);
        if (lane == 0) ws[WS_X + r] = fmaxf(s + comb_b[r], 0.f);
    }
}

// 256 blocks * 4 outputs: gi rows (r,z,n) + gate math -> h_new
__global__ __launch_bounds__(256) void k_gru(const float* __restrict__ wih,
                                             const float* __restrict__ bih,
                                             float* __restrict__ ws) {
    __shared__ __align__(16) float s_x[H];
    const int t = threadIdx.x, wave = t >> 6, lane = t & 63;
    for (int j = t; j < H; j += 256) s_x[j] = ws[WS_X + j];
    __syncthreads();
    const float4* x4 = (const float4*)s_x;
    const int i = blockIdx.x * 4 + wave;                // 0..1023
    float g[3];
    for (int p = 0; p < 3; ++p) {
        const float4* w4 = (const float4*)(wih + (size_t)(i + p * H) * H);
        float s = 0.f;
        for (int m = 0; m < 4; ++m) {
            int j = lane + (m << 6);
            float4 a = w4[j], b = x4[j];
            s += a.x * b.x + a.y * b.y + a.z * b.z + a.w * b.w;
        }
        for (int o = 32; o; o >>= 1) s += __shfl_down(s, o);
        g[p] = s;
    }
    if (lane == 0) {
        float gr = g[0] + bih[i]         + ws[WS_GH + i];
        float gz = g[1] + bih[i + H]     + ws[WS_GH + i + H];
        float gn = g[2] + bih[i + 2*H];
        float r = 1.f / (1.f + expf(-gr));
        float z = 1.f / (1.f + expf(-gz));
        float n = tanhf(gn + r * ws[WS_GH + i + 2*H]);
        ws[WS_HNEW + i] = (1.f - z) * n + z * ws[WS_H + i];
    }
}

// NB_OUT blocks * 99 rows: logits + per-block argmax partial
__global__ __launch_bounds__(256) void k_logits(const float* __restrict__ out_w,
                                                const float* __restrict__ out_b,
                                                float* __restrict__ ws) {
    __shared__ __align__(16) float s_h[H];
    __shared__ float s_bv[4];
    __shared__ int   s_bi[4];
    const int t = threadIdx.x, wave = t >> 6, lane = t & 63;
    for (int j = t; j < H; j += 256) s_h[j] = ws[WS_HNEW + j];
    __syncthreads();
    const float4* h4 = (const float4*)s_h;
    const int base = blockIdx.x * 99;
    const int end  = min(base + 99, V);
    float bv = -INFINITY; int bi = 0x7fffffff;
    for (int r0 = base + wave; r0 < end; r0 += 4) {
        const float4* w4 = (const float4*)(out_w + (size_t)r0 * H);
        float s = 0.f;
        for (int m = 0; m < 4; ++m) {
            int j = lane + (m << 6);
            float4 a = w4[j], b = h4[j];
            s += a.x * b.x + a.y * b.y + a.z * b.z + a.w * b.w;
        }
        for (int o = 32; o; o >>= 1) s += __shfl_xor(s, o);  // all lanes get sum
        s += out_b[r0];
        if (s > bv) { bv = s; bi = r0; }   // rows increase -> first max kept
    }
    if (lane == 0) { s_bv[wave] = bv; s_bi[wave] = bi; }
    __syncthreads();
    if (t == 0) {
        for (int w2 = 1; w2 < 4; ++w2) {
            float v = s_bv[w2]; int i2 = s_bi[w2];
            if (v > bv || (v == bv && i2 < bi)) { bv = v; bi = i2; }
        }
        ws[WS_PMAX + blockIdx.x] = bv;
        ((int*)(ws + WS_PIDX))[blockIdx.x] = bi;
    }
}

// single block: final argmax + state update
__global__ __launch_bounds__(512) void k_reduce(float* __restrict__ ws,
                                                int* __restrict__ out, int step) {
    __shared__ float s_v[512];
    __shared__ int   s_i[512];
    __shared__ int   s_done;
    const int t = threadIdx.x;
    s_v[t] = (t < NB_OUT) ? ws[WS_PMAX + t] : -INFINITY;
    s_i[t] = (t < NB_OUT) ? ((int*)(ws + WS_PIDX))[t] : 0x7fffffff;
    if (t == 0) s_done = ((int*)(ws + WS_DONE))[0];
    __syncthreads();
    for (int o = 256; o; o >>= 1) {
        if (t < o) {
            float v2 = s_v[t + o]; int i2 = s_i[t + o];
            if (v2 > s_v[t] || (v2 == s_v[t] && i2 < s_i[t])) { s_v[t] = v2; s_i[t] = i2; }
        }
        __syncthreads();
    }
    const int top = s_i[0];
    const int done_old = s_done;
    if (!done_old) {                       // h_next = done ? h : h_new (OLD done)
        ws[WS_H + t]       = ws[WS_HNEW + t];
        ws[WS_H + t + 512] = ws[WS_HNEW + t + 512];
    }
    if (t == 0) {
        out[step] = done_old ? 0 : top;
        ((int*)(ws + WS_TOK))[0]  = top;
        ((int*)(ws + WS_DONE))[0] = done_old | (top == 1) | (top == STOP_ID);
    }
}

extern "C" void kernel_launch(void* const* d_in, const int* in_sizes, int n_in,
                              void* d_out, int out_size, void* d_ws, size_t ws_size,
                              hipStream_t stream) {
    const int*   dec_in = (const int*)  d_in[0];
    const float* h0     = (const float*)d_in[1];
    const float* enc    = (const float*)d_in[2];
    const float* emb    = (const float*)d_in[3];
    const float* attn_w = (const float*)d_in[4];
    const float* attn_b = (const float*)d_in[5];
    const float* comb_w = (const float*)d_in[6];
    const float* comb_b = (const float*)d_in[7];
    const float* wih    = (const float*)d_in[8];
    const float* whh    = (const float*)d_in[9];
    const float* bih    = (const float*)d_in[10];
    const float* bhh    = (const float*)d_in[11];
    const float* out_w  = (const float*)d_in[12];
    const float* out_b  = (const float*)d_in[13];
    float* ws = (float*)d_ws;
    int*   out = (int*)d_out;

    k_init<<<1, 1024, 0, stream>>>(dec_in, h0, ws);
    for (int step = 0; step < STEPS; ++step) {
        k_pre<<<800, 256, 0, stream>>>(emb, attn_w, attn_b, whh, bhh, ws);
        k_ctx_comb<<<64, 256, 0, stream>>>(emb, enc, comb_w, comb_b, ws);
        k_gru<<<256, 256, 0, stream>>>(wih, bih, ws);
        k_logits<<<NB_OUT, 256, 0, stream>>>(out_w, out_b, ws);
        k_reduce<<<1, 512, 0, stream>>>(ws, out, step);
    }
}